// Round 7
// baseline (21.881 us; speedup 1.0000x reference)
//
#include <hip/hip_runtime.h>
#include <math.h>

// Problem constants
#define NN 128
#define LL 1024
#define HH 4
#define DD 64
#define NCHUNK 8          // chunks per n (128 rows each)
#define CROWS 128

// workspace layout (floats)
//   Zt  : [256(p=h*64+k)][64 q]   @ 0       (16384)
//   cv  : [N][32(hj)]             @ 16384   (4096)
//   Wtb : [N][32(hj)][64 k] bf16  @ 20480
#define WS_ZT  0
#define WS_C   16384
#define WS_WTB 20480

typedef __attribute__((ext_vector_type(8))) short short8;
typedef __attribute__((ext_vector_type(4))) float f32x4;

__device__ __forceinline__ float sigm(float x) {
    return __builtin_amdgcn_rcpf(1.f + __expf(-x));
}

__device__ __forceinline__ unsigned short f2bf(float x) {
    union { float f; unsigned u; } v; v.f = x;
    unsigned r = v.u + 0x7FFFu + ((v.u >> 16) & 1u);   // RNE
    return (unsigned short)(r >> 16);
}

__device__ __forceinline__ short8 pack_bf8(float4 a, float4 b) {
    short8 r;
    r[0] = (short)f2bf(a.x); r[1] = (short)f2bf(a.y);
    r[2] = (short)f2bf(a.z); r[3] = (short)f2bf(a.w);
    r[4] = (short)f2bf(b.x); r[5] = (short)f2bf(b.y);
    r[6] = (short)f2bf(b.z); r[7] = (short)f2bf(b.w);
    return r;
}

// ---------------------------------------------------------------------------
// K1: blocks 0..31   : out[n,q] = bu[q]          (init for K2's atomics)
//     blocks 32..95  : Zt[p,q]  = sum_d Wu[q,h*64+d]*Wv[h*64+d,k]  (p=h*64+k)
//     blocks 96..607 : per-(n,h) v, w, c, Wt(bf16, [hj][k] layout)
// ---------------------------------------------------------------------------
__global__ void __launch_bounds__(256) precompute_kernel(
    const float* __restrict__ target, const float* __restrict__ memv,
    const float* __restrict__ Wk, const float* __restrict__ Wq,
    const float* __restrict__ Wv, const float* __restrict__ Wu,
    const float* __restrict__ W1, const float* __restrict__ b1,
    const float* __restrict__ bu,
    unsigned short* __restrict__ Wtb, float* __restrict__ cvg,
    float* __restrict__ Zt, float* __restrict__ out)
{
    const int b = blockIdx.x;
    const int t = threadIdx.x;

    if (b < 32) {
        const int idx = b * 256 + t;          // 8192 = 128*64
        out[idx] = bu[idx & 63];
        return;
    }
    if (b < 96) {
        // Zt: q = b-32; t = p = h*64+k. Wv read coalesced (k on lanes).
        const int q = b - 32;
        const int h = t >> 6, k = t & 63;
        float s = 0.f;
        #pragma unroll 8
        for (int d = 0; d < 64; ++d)
            s = fmaf(Wu[q * 256 + h * 64 + d], Wv[(h * 64 + d) * 64 + k], s);
        Zt[t * 64 + q] = s;
        return;
    }

    const int nh = b - 96;
    const int n = nh >> 2, h = nh & 3;

    __shared__ __align__(16) float tl[64];
    __shared__ __align__(16) float ml[64];
    __shared__ float vh[64];
    __shared__ float wh[64 * 8];              // [d][j]
    __shared__ float cp[64];

    if (t < 64)       tl[t] = target[n * 64 + t];
    else if (t < 128) ml[t - 64] = memv[n * 64 + (t - 64)];
    __syncthreads();

    // ---- v[d] = sum_k Wq[h*64+d, k] * target[k]; (d, k-quarter) on threads ----
    {
        const int d = t >> 2, kq = t & 3;
        const float4* wq4 = reinterpret_cast<const float4*>(Wq + (h * 64 + d) * 64 + kq * 16);
        const float4* tl4 = reinterpret_cast<const float4*>(tl + kq * 16);
        float s = 0.f;
        #pragma unroll
        for (int c = 0; c < 4; ++c) {
            const float4 a = wq4[c], bb = tl4[c];
            s = fmaf(a.x, bb.x, s); s = fmaf(a.y, bb.y, s);
            s = fmaf(a.z, bb.z, s); s = fmaf(a.w, bb.w, s);
        }
        s += __shfl_xor(s, 1);
        s += __shfl_xor(s, 2);
        if (kq == 0) vh[d] = s;
    }
    __syncthreads();

    // ---- w[d][j] = -W1[j,d] - W1[j,128+d] + W1[j,64+d]*v[d] + W1[j,192+d]*m[d] ----
    {
        const int d = t & 63, jh = t >> 6;
        const float vv = vh[d], mm = ml[d];
        #pragma unroll
        for (int r = 0; r < 2; ++r) {
            const int j = jh + r * 4;
            float wv = -W1[j * 256 + d] - W1[j * 256 + 128 + d];
            wv = fmaf(W1[j * 256 + 64 + d], vv, wv);
            wv = fmaf(W1[j * 256 + 192 + d], mm, wv);
            wh[d * 8 + j] = wv;
        }
    }
    // ---- c[j] partials ----
    if (t < 64) {
        const int j = t >> 3, sl = t & 7;
        float s = 0.f;
        #pragma unroll
        for (int d8 = 0; d8 < 8; ++d8) {
            const int d = sl * 8 + d8;
            s = fmaf(W1[j * 256 + d], vh[d], s);
            s = fmaf(W1[j * 256 + 128 + d], ml[d], s);
        }
        cp[t] = s;
    }
    __syncthreads();
    if (t < 8) {
        float s = b1[t];
        #pragma unroll
        for (int sl = 0; sl < 8; ++sl) s += cp[t * 8 + sl];
        cvg[n * 32 + h * 8 + t] = s;
    }

    // ---- Wt[hj][k] = sum_d Wk[h*64+d, k] * w[d][j]; k on lanes (coalesced) ----
    {
        const int k = t & 63, jp = t >> 6;
        float s0 = 0.f, s1 = 0.f;
        #pragma unroll 8
        for (int d = 0; d < 64; ++d) {
            const float wk = Wk[(h * 64 + d) * 64 + k];
            s0 = fmaf(wk, wh[d * 8 + jp], s0);       // uniform LDS reads
            s1 = fmaf(wk, wh[d * 8 + jp + 4], s1);
        }
        unsigned short* dst = Wtb + ((size_t)n * 32 + h * 8) * 64;
        dst[jp * 64 + k]       = f2bf(s0);
        dst[(jp + 4) * 64 + k] = f2bf(s1);
    }
}

// ---------------------------------------------------------------------------
// K2: per (n, 128-row chunk):
//   stage seq chunk as bf16 in LDS (coalesced global float4 -> pack -> b128)
//   score GEMM via MFMA: S^T[hj, l] = Wt[hj,:k] . seq[l,:k]^T
//     A-frag = Wt bf16 (LDS), B-frag = seq bf16 (LDS, row stride 72)
//   -> sigmoid MLP (j-reduce via shfl_xor 16) -> att_l[l][h]
//   -> T[h][k] = sum_l att*seq (fp32 seq re-read from global, coalesced/L2)
//   -> out[q] += sum_p T[p]*Zt[p][q]  (atomic)
// ---------------------------------------------------------------------------
__global__ void __launch_bounds__(256, 4) main_kernel(
    const float* __restrict__ seq, const unsigned short* __restrict__ Wtb,
    const float* __restrict__ cvg, const float* __restrict__ W2,
    const float* __restrict__ b2, const float* __restrict__ Zt,
    float* __restrict__ att_out, float* __restrict__ out)
{
    const int n = blockIdx.x >> 3;
    const int chunk = blockIdx.x & 7;
    const int l0 = chunk * CROWS;
    const int t = threadIdx.x;
    const int lane = t & 63;
    const int w = t >> 6;

    __shared__ __align__(16) short seq_bf[128 * 72];  // [l][k] bf16, 144B rows
    __shared__ __align__(16) short wt_lds[32 * 72];   // [hj][k] bf16
    __shared__ float cvl[32];
    __shared__ __align__(16) float att_l[512];        // [l][h]
    __shared__ __align__(16) float Tp_l[4][256];      // per-wave partial T
    __shared__ float T_l[256];                        // [p = h*64+k]
    __shared__ float op[256];
    // total ~31.4 KB

    const float* sbase = seq + ((size_t)n * LL + l0) * 64;

    // ---- stage seq chunk as bf16: 4 x (two float4 = 32B contig per thread) ----
    #pragma unroll
    for (int g = 0; g < 4; ++g) {
        const int p4 = g * 256 + t;           // 8-float group id (1024 total)
        const int l = p4 >> 3, seg = p4 & 7;
        const float* rp = sbase + l * 64 + seg * 8;
        const float4 a = *reinterpret_cast<const float4*>(rp);
        const float4 bb = *reinterpret_cast<const float4*>(rp + 4);
        *reinterpret_cast<short8*>(seq_bf + l * 72 + seg * 8) = pack_bf8(a, bb);
    }
    // ---- stage Wt (bf16, 4KB) + cv ----
    {
        const int row = t >> 3, seg = t & 7;
        const int4 wv = *reinterpret_cast<const int4*>(
            Wtb + ((size_t)n * 32 + row) * 64 + seg * 8);
        *reinterpret_cast<int4*>(wt_lds + row * 72 + seg * 8) = wv;
    }
    if (t < 32) cvl[t] = cvg[n * 32 + t];
    __syncthreads();

    // ---- score MFMAs: wave w -> rowtile rt (hj 16-block), coltiles ctbase..+3 ----
    const int rt = w & 1;
    const int ctbase = (w >> 1) * 4;
    const int g = lane >> 4;          // k-group / C-row group
    const int cidx = lane & 15;       // col within tile

    short8 afrag[2];
    #pragma unroll
    for (int ks = 0; ks < 2; ++ks)
        afrag[ks] = *reinterpret_cast<const short8*>(
            wt_lds + (rt * 16 + cidx) * 72 + ks * 32 + g * 8);

    f32x4 acc[4];
    #pragma unroll
    for (int ct = 0; ct < 4; ++ct)
        #pragma unroll
        for (int r = 0; r < 4; ++r)
            acc[ct][r] = cvl[rt * 16 + g * 4 + r];

    #pragma unroll
    for (int ct = 0; ct < 4; ++ct) {
        const int l = (ctbase + ct) * 16 + cidx;
        const short8 bf0 = *reinterpret_cast<const short8*>(seq_bf + l * 72 + g * 8);
        const short8 bf1 = *reinterpret_cast<const short8*>(seq_bf + l * 72 + 32 + g * 8);
        acc[ct] = __builtin_amdgcn_mfma_f32_16x16x32_bf16(afrag[0], bf0, acc[ct], 0, 0, 0);
        acc[ct] = __builtin_amdgcn_mfma_f32_16x16x32_bf16(afrag[1], bf1, acc[ct], 0, 0, 0);
    }

    // ---- MLP: hmid = sigm(score); partial j-sum; partner group via shfl_xor 16 ----
    {
        const float4 w2v = *reinterpret_cast<const float4*>(W2 + 4 * (g & 1));
        const float b2v = b2[0];
        #pragma unroll
        for (int ct = 0; ct < 4; ++ct) {
            float local = w2v.x * sigm(acc[ct][0]);
            local = fmaf(w2v.y, sigm(acc[ct][1]), local);
            local = fmaf(w2v.z, sigm(acc[ct][2]), local);
            local = fmaf(w2v.w, sigm(acc[ct][3]), local);
            local += __shfl_xor(local, 16);
            const float attv = sigm(b2v + local);
            if ((lane & 16) == 0) {
                const int l = (ctbase + ct) * 16 + cidx;
                const int h = 2 * rt + (g >> 1);
                att_l[l * 4 + h] = attv;
            }
        }
    }
    __syncthreads();

    // ---- att store: 512 contiguous floats ([l][h] == reference layout) ----
    {
        float* dst = att_out + ((size_t)n * LL + l0) * 4;
        dst[t] = att_l[t];
        dst[256 + t] = att_l[256 + t];
    }

    // ---- T partials: wave w covers l in [32w, 32w+32); lane = k (fp32 seq) ----
    {
        float th0 = 0.f, th1 = 0.f, th2 = 0.f, th3 = 0.f;
        const float* sq = sbase + (w * 32) * 64 + lane;
        #pragma unroll 4
        for (int li = 0; li < 32; ++li) {
            const float s = sq[li * 64];                      // coalesced, L2-hot
            const float4 a = *reinterpret_cast<const float4*>(att_l + (w * 32 + li) * 4);
            th0 = fmaf(a.x, s, th0); th1 = fmaf(a.y, s, th1);
            th2 = fmaf(a.z, s, th2); th3 = fmaf(a.w, s, th3);
        }
        Tp_l[w][0 * 64 + lane] = th0;
        Tp_l[w][1 * 64 + lane] = th1;
        Tp_l[w][2 * 64 + lane] = th2;
        Tp_l[w][3 * 64 + lane] = th3;
    }
    __syncthreads();

    T_l[t] = Tp_l[0][t] + Tp_l[1][t] + Tp_l[2][t] + Tp_l[3][t];
    __syncthreads();

    // ---- out[q] += sum_p T[p] * Zt[p][q]; Zt lane-coalesced, T uniform ----
    {
        const int q = t & 63, wq = t >> 6;
        float s = 0.f;
        #pragma unroll 8
        for (int i = 0; i < 64; ++i) {
            const int p = wq * 64 + i;
            s = fmaf(T_l[p], Zt[p * 64 + q], s);
        }
        op[t] = s;
    }
    __syncthreads();
    if (t < 64) {
        const float s = op[t] + op[64 + t] + op[128 + t] + op[192 + t];
        atomicAdd(out + n * 64 + t, s);
    }
}

extern "C" void kernel_launch(void* const* d_in, const int* in_sizes, int n_in,
                              void* d_out, int out_size, void* d_ws, size_t ws_size,
                              hipStream_t stream) {
    const float* seq    = (const float*)d_in[0];
    const float* target = (const float*)d_in[1];
    const float* memv   = (const float*)d_in[2];
    const float* Wk     = (const float*)d_in[3];
    const float* Wq     = (const float*)d_in[4];
    const float* Wv     = (const float*)d_in[5];
    const float* Wu     = (const float*)d_in[6];
    const float* bu     = (const float*)d_in[7];
    const float* W1     = (const float*)d_in[8];
    const float* b1     = (const float*)d_in[9];
    const float* W2     = (const float*)d_in[10];
    const float* b2     = (const float*)d_in[11];

    float* out = (float*)d_out;             // [128*64]
    float* att = out + NN * DD;             // [128*1024*4]

    float* ws  = (float*)d_ws;
    float* Ztw = ws + WS_ZT;
    float* cvg = ws + WS_C;
    unsigned short* Wtb = (unsigned short*)(ws + WS_WTB);

    precompute_kernel<<<608, 256, 0, stream>>>(target, memv, Wk, Wq, Wv, Wu, W1, b1,
                                               bu, Wtb, cvg, Ztw, out);
    main_kernel<<<NN * NCHUNK, 256, 0, stream>>>(seq, Wtb, cvg, W2, b2, Ztw,
                                                 att, out);
}